// Round 8
// baseline (644.237 us; speedup 1.0000x reference)
//
#include <hip/hip_runtime.h>

typedef __attribute__((ext_vector_type(8))) short bf16x8;
typedef __attribute__((ext_vector_type(4))) float f32x4;

#define MFMA(a, b, c) __builtin_amdgcn_mfma_f32_16x16x32_bf16(a, b, c, 0, 0, 0)

// f32 pair -> packed bf16x2, RTNE (bit trick; verified rounds 1-6)
__device__ __forceinline__ unsigned int pack2(float x, float y) {
  union { float f; unsigned u; } a{x}, b{y};
  unsigned ax = a.u + 0x7FFFu + ((a.u >> 16) & 1u);
  unsigned bx = b.u + 0x7FFFu + ((b.u >> 16) & 1u);
  return (ax >> 16) | (bx & 0xFFFF0000u);
}
__device__ __forceinline__ unsigned short f2bf(float x) {
  union { float f; unsigned u; } a{x};
  unsigned r = a.u + 0x7FFFu + ((a.u >> 16) & 1u);
  return (unsigned short)(r >> 16);
}
// pack two f32x4 (j=0..3 from a, j=4..7 from b) into one bf16x8 fragment
__device__ __forceinline__ bf16x8 pack8(f32x4 a, f32x4 b) {
  union { unsigned u[4]; bf16x8 v; } r;
  r.u[0] = pack2(a[0], a[1]); r.u[1] = pack2(a[2], a[3]);
  r.u[2] = pack2(b[0], b[1]); r.u[3] = pack2(b[2], b[3]);
  return r.v;
}

// token t (shifted-window order) -> flat pixel base offset (elements) in x / y
__device__ __forceinline__ int src_off(int t) {
  int wi = t >> 6, n = t & 63;
  int b = wi >> 10, wr = (wi >> 5) & 31, wc = wi & 31;
  int hh = (wr * 8 + (n >> 3) + 4) & 255;
  int ww = (wc * 8 + (n & 7) + 4) & 255;
  return ((((b << 8) | hh) << 8) | ww) << 8;
}

// ---- prep: weight transposes (bf16) + fragment-ordered relative bias ------
// rb2[h][mt][nt][g][ln][jr] = bias(q = 16*nt+ln, k = 16*mt+4*g+jr)  [S^T order]
__global__ __launch_bounds__(256) void prep_kernel(
    const float* __restrict__ w_qkv, const float* __restrict__ w_proj,
    const float* __restrict__ bias_table,
    unsigned short* __restrict__ wqkvt, unsigned short* __restrict__ wpt,
    float* __restrict__ rb2) {
  int i = blockIdx.x * 256 + threadIdx.x;
  if (i < 196608) {                        // wqkvt[n][k] = w_qkv[k][n]
    wqkvt[i] = f2bf(w_qkv[(i & 255) * 768 + (i >> 8)]);
  } else if (i < 262144) {                 // wpt[n][k] = w_proj[k][n]
    int j = i - 196608;
    wpt[j] = f2bf(w_proj[(j & 255) * 256 + (j >> 8)]);
  } else {
    int j = i - 262144;
    int jr = j & 3, ln = (j >> 2) & 15, g = (j >> 6) & 3;
    int nt = (j >> 8) & 3, mt = (j >> 10) & 3, h = j >> 12;
    int q = 16 * nt + ln;                  // query token
    int k = 16 * mt + 4 * g + jr;          // key token
    int idx = ((q >> 3) - (k >> 3) + 7) * 15 + ((q & 7) - (k & 7) + 7);
    rb2[j] = bias_table[idx * 8 + h];
  }
}

// ---- fused: stage x -> Q/K -> S^T -> softmax -> V -> PV -> proj -----------
__global__ __launch_bounds__(512, 4) void fused_kernel(
    const float* __restrict__ x, const unsigned short* __restrict__ wqkvt,
    const float* __restrict__ b_qkv, const unsigned short* __restrict__ wpt,
    const float* __restrict__ b_proj, const float* __restrict__ rb2,
    float* __restrict__ y) {
  // LDS: XL [64][256] bf16 swizzled at 0 (32 KiB); per-wave AO [64][40] at 16384+h*2560
  __shared__ unsigned short sm[36864];     // 72 KiB -> 2 blocks/CU
  int wi = blockIdx.x;
  int tid = threadIdx.x;
  int h = tid >> 6, lane = tid & 63, ln = lane & 15, g = lane >> 4;
  unsigned short* R1 = sm + 16384 + h * 2560;

  // -------- phase 0: stage window x -> XL bf16 (swizzled) --------
  int tb = wi * 64;
#pragma unroll
  for (int r = 0; r < 2; ++r) {
    int u = tid + 512 * r;
    int tok = u >> 4, ck = u & 15;
    const float4* s4 = (const float4*)(x + src_off(tb + tok) + ck * 16);
    float4 f0 = s4[0], f1 = s4[1], f2 = s4[2], f3 = s4[3];
    uint4 w0, w1;
    w0.x = pack2(f0.x, f0.y); w0.y = pack2(f0.z, f0.w);
    w0.z = pack2(f1.x, f1.y); w0.w = pack2(f1.z, f1.w);
    w1.x = pack2(f2.x, f2.y); w1.y = pack2(f2.z, f2.w);
    w1.z = pack2(f3.x, f3.y); w1.w = pack2(f3.z, f3.w);
    int base = tok * 512 + ck * 32, swz = (tok & 7) << 4;
    *(uint4*)((char*)sm + ((base) ^ swz)) = w0;
    *(uint4*)((char*)sm + ((base + 16) ^ swz)) = w1;
  }
  __syncthreads();

  // -------- pass Q/K (transposed: M = head-dim d, N = tokens) --------
  bf16x8 qf[4], kf[4];
  {
    f32x4 accq[2][4] = {}, acck[2][4] = {};
#pragma unroll
    for (int ks = 0; ks < 8; ++ks) {
      bf16x8 xf[4];
#pragma unroll
      for (int t = 0; t < 4; ++t) {
        int row = 16 * t + ln;
        xf[t] = *(const bf16x8*)((char*)sm + ((row * 512 + ks * 64 + 16 * g) ^ ((row & 7) << 4)));
      }
      bf16x8 wq[2], wk[2];
#pragma unroll
      for (int mt = 0; mt < 2; ++mt) {
        int nr = 32 * h + 16 * mt + ln;
        wq[mt] = *(const bf16x8*)(wqkvt + nr * 256 + ks * 32 + 8 * g);
        wk[mt] = *(const bf16x8*)(wqkvt + (256 + nr) * 256 + ks * 32 + 8 * g);
      }
#pragma unroll
      for (int mt = 0; mt < 2; ++mt)
#pragma unroll
        for (int nt = 0; nt < 4; ++nt) {
          accq[mt][nt] = MFMA(wq[mt], xf[nt], accq[mt][nt]);
          acck[mt][nt] = MFMA(wk[mt], xf[nt], acck[mt][nt]);
        }
    }
    f32x4 bq0 = *(const f32x4*)(b_qkv + 32 * h + 4 * g);
    f32x4 bq1 = *(const f32x4*)(b_qkv + 32 * h + 16 + 4 * g);
    f32x4 bk0 = *(const f32x4*)(b_qkv + 256 + 32 * h + 4 * g);
    f32x4 bk1 = *(const f32x4*)(b_qkv + 256 + 32 * h + 16 + 4 * g);
    const float sc = 0.17677669529663687f;
#pragma unroll
    for (int nt = 0; nt < 4; ++nt) {
      qf[nt] = pack8((accq[0][nt] + bq0) * sc, (accq[1][nt] + bq1) * sc);
      kf[nt] = pack8(acck[0][nt] + bk0, acck[1][nt] + bk1);
    }
  }

  // -------- S^T = K·Q^T with bias preloaded --------
  f32x4 st[4][4];
  const float* rbw = rb2 + h * 4096;
#pragma unroll
  for (int mt = 0; mt < 4; ++mt)
#pragma unroll
    for (int nt = 0; nt < 4; ++nt)
      st[mt][nt] = *(const f32x4*)(rbw + ((((mt * 4 + nt) * 4 + g) * 16 + ln) * 4));
#pragma unroll
  for (int mt = 0; mt < 4; ++mt)
#pragma unroll
    for (int nt = 0; nt < 4; ++nt)
      st[mt][nt] = MFMA(kf[mt], qf[nt], st[mt][nt]);

  // -------- softmax + progressive bf16 pack (st -> pb, frees 32 regs) ------
  bf16x8 pb[2][4];
#pragma unroll
  for (int nt = 0; nt < 4; ++nt) {
    float mx = st[0][nt][0];
#pragma unroll
    for (int mt = 0; mt < 4; ++mt)
#pragma unroll
      for (int jr = 0; jr < 4; ++jr) mx = fmaxf(mx, st[mt][nt][jr]);
    mx = fmaxf(mx, __shfl_xor(mx, 16));
    mx = fmaxf(mx, __shfl_xor(mx, 32));
    float sum = 0.f;
#pragma unroll
    for (int mt = 0; mt < 4; ++mt)
#pragma unroll
      for (int jr = 0; jr < 4; ++jr) {
        float p = __expf(st[mt][nt][jr] - mx);
        st[mt][nt][jr] = p; sum += p;
      }
    sum += __shfl_xor(sum, 16);
    sum += __shfl_xor(sum, 32);
    float inv = 1.f / sum;
    pb[0][nt] = pack8(st[0][nt] * inv, st[1][nt] * inv);
    pb[1][nt] = pack8(st[2][nt] * inv, st[3][nt] * inv);
  }

  // -------- pass V (after softmax; st's registers are free again) --------
  f32x4 av[4][2] = {};
#pragma unroll
  for (int ks = 0; ks < 8; ++ks) {
    bf16x8 xf[4];
#pragma unroll
    for (int t = 0; t < 4; ++t) {
      int row = 16 * t + ln;
      xf[t] = *(const bf16x8*)((char*)sm + ((row * 512 + ks * 64 + 16 * g) ^ ((row & 7) << 4)));
    }
    bf16x8 wv[2];
#pragma unroll
    for (int dt = 0; dt < 2; ++dt)
      wv[dt] = *(const bf16x8*)(wqkvt + (512 + 32 * h + 16 * dt + ln) * 256 + ks * 32 + 8 * g);
#pragma unroll
    for (int mt = 0; mt < 4; ++mt)
#pragma unroll
      for (int dt = 0; dt < 2; ++dt)
        av[mt][dt] = MFMA(xf[mt], wv[dt], av[mt][dt]);
  }

  // -------- PV: O^T = V^T · P^T; V^T frags packed DIRECTLY from av ---------
  // vf[kk][dt] = pack8(av[2kk][dt]+bv, av[2kk+1][dt]+bv) — pi_A == pi_B
  // (round-4-verified identity; no LDS round-trip)
  f32x4 o[2][4] = {};
  {
    float b0 = b_qkv[512 + 32 * h + ln], b1 = b_qkv[512 + 32 * h + 16 + ln];
    f32x4 bv0 = {b0, b0, b0, b0}, bv1 = {b1, b1, b1, b1};
#pragma unroll
    for (int kk = 0; kk < 2; ++kk) {
      bf16x8 vf0 = pack8(av[2 * kk][0] + bv0, av[2 * kk + 1][0] + bv0);
      bf16x8 vf1 = pack8(av[2 * kk][1] + bv1, av[2 * kk + 1][1] + bv1);
#pragma unroll
      for (int nt = 0; nt < 4; ++nt) {
        o[0][nt] = MFMA(vf0, pb[kk][nt], o[0][nt]);
        o[1][nt] = MFMA(vf1, pb[kk][nt], o[1][nt]);
      }
    }
  }

  // -------- AO -> per-wave LDS (only remaining round-trip) --------
#pragma unroll
  for (int dt = 0; dt < 2; ++dt)
#pragma unroll
    for (int nt = 0; nt < 4; ++nt) {
      uint2 vp;
      vp.x = pack2(o[dt][nt][0], o[dt][nt][1]);
      vp.y = pack2(o[dt][nt][2], o[dt][nt][3]);
      *(uint2*)&R1[(16 * nt + ln) * 40 + 16 * dt + 4 * g] = vp;
    }
  __syncthreads();

  // -------- proj: K-step ks = head ks's AO region --------
  f32x4 a2[4][2] = {};
#pragma unroll
  for (int ks = 0; ks < 8; ++ks) {
    const unsigned short* AO = sm + 16384 + ks * 2560;
    bf16x8 af2[4], bf2[2];
#pragma unroll
    for (int mt = 0; mt < 4; ++mt)
      af2[mt] = *(const bf16x8*)&AO[(16 * mt + ln) * 40 + 8 * g];
#pragma unroll
    for (int nt = 0; nt < 2; ++nt)
      bf2[nt] = *(const bf16x8*)(wpt + (32 * h + 16 * nt + ln) * 256 + ks * 32 + 8 * g);
#pragma unroll
    for (int mt = 0; mt < 4; ++mt) {
      a2[mt][0] = MFMA(af2[mt], bf2[0], a2[mt][0]);
      a2[mt][1] = MFMA(af2[mt], bf2[1], a2[mt][1]);
    }
  }
  // epilogue: un-shift scatter + proj bias (hoisted address bases)
  // n = 16mt+4g+jr:  n>>3 = 2mt+(g>>1),  n&7 = 4(g&1)+jr
  int b = wi >> 10, wr = (wi >> 5) & 31, wc = wi & 31;
  int hb = wr * 8 + (g >> 1) + 4;
  int wb = wc * 8 + 4 * (g & 1) + 4;
  int colb = 32 * h + ln;
  float bp0 = b_proj[colb], bp1 = b_proj[colb + 16];
#pragma unroll
  for (int mt = 0; mt < 4; ++mt) {
    int hh = (hb + 2 * mt) & 255;
#pragma unroll
    for (int jr = 0; jr < 4; ++jr) {
      int ww = (wb + jr) & 255;
      float* yp = y + (((((b << 8) | hh) << 8) | ww) << 8) + colb;
      yp[0]  = a2[mt][0][jr] + bp0;
      yp[16] = a2[mt][1][jr] + bp1;
    }
  }
}

extern "C" void kernel_launch(void* const* d_in, const int* in_sizes, int n_in,
                              void* d_out, int out_size, void* d_ws, size_t ws_size,
                              hipStream_t stream) {
  const float* x          = (const float*)d_in[0];
  const float* w_qkv      = (const float*)d_in[1];
  const float* b_qkv      = (const float*)d_in[2];
  const float* w_proj     = (const float*)d_in[3];
  const float* b_proj     = (const float*)d_in[4];
  const float* bias_table = (const float*)d_in[5];
  char* ws = (char*)d_ws;
  // ws layout: wqkvt 384 KiB | wpt 128 KiB | rb2 128 KiB
  unsigned short* wqkvt = (unsigned short*)(ws);
  unsigned short* wpt   = (unsigned short*)(ws + 393216);
  float* rb2            = (float*)(ws + 524288);
  float* y = (float*)d_out;

  prep_kernel<<<1152, 256, 0, stream>>>(w_qkv, w_proj, bias_table, wqkvt, wpt, rb2);
  fused_kernel<<<4096, 512, 0, stream>>>(x, wqkvt, b_qkv, wpt, b_proj, rb2, y);
}

// Round 9
// 325.263 us; speedup vs baseline: 1.9807x; 1.9807x over previous
//
#include <hip/hip_runtime.h>

typedef __attribute__((ext_vector_type(8))) short bf16x8;
typedef __attribute__((ext_vector_type(4))) float f32x4;

#define MFMA(a, b, c) __builtin_amdgcn_mfma_f32_16x16x32_bf16(a, b, c, 0, 0, 0)

// f32 pair -> packed bf16x2, RTNE (bit trick; verified rounds 1-6)
__device__ __forceinline__ unsigned int pack2(float x, float y) {
  union { float f; unsigned u; } a{x}, b{y};
  unsigned ax = a.u + 0x7FFFu + ((a.u >> 16) & 1u);
  unsigned bx = b.u + 0x7FFFu + ((b.u >> 16) & 1u);
  return (ax >> 16) | (bx & 0xFFFF0000u);
}
__device__ __forceinline__ unsigned short f2bf(float x) {
  union { float f; unsigned u; } a{x};
  unsigned r = a.u + 0x7FFFu + ((a.u >> 16) & 1u);
  return (unsigned short)(r >> 16);
}
// pack two f32x4 (j=0..3 from a, j=4..7 from b) into one bf16x8 fragment
__device__ __forceinline__ bf16x8 pack8(f32x4 a, f32x4 b) {
  union { unsigned u[4]; bf16x8 v; } r;
  r.u[0] = pack2(a[0], a[1]); r.u[1] = pack2(a[2], a[3]);
  r.u[2] = pack2(b[0], b[1]); r.u[3] = pack2(b[2], b[3]);
  return r.v;
}

// token t (shifted-window order) -> flat pixel base offset (elements) in x / y
__device__ __forceinline__ int src_off(int t) {
  int wi = t >> 6, n = t & 63;
  int b = wi >> 10, wr = (wi >> 5) & 31, wc = wi & 31;
  int hh = (wr * 8 + (n >> 3) + 4) & 255;
  int ww = (wc * 8 + (n & 7) + 4) & 255;
  return ((((b << 8) | hh) << 8) | ww) << 8;
}

// ---- prep: weight transposes (bf16) + fragment-ordered relative bias ------
// rb2[h][mt][nt][g][ln][jr] = bias(q = 16*nt+ln, k = 16*mt+4*g+jr)  [S^T order]
__global__ __launch_bounds__(256) void prep_kernel(
    const float* __restrict__ w_qkv, const float* __restrict__ w_proj,
    const float* __restrict__ bias_table,
    unsigned short* __restrict__ wqkvt, unsigned short* __restrict__ wpt,
    float* __restrict__ rb2) {
  int i = blockIdx.x * 256 + threadIdx.x;
  if (i < 196608) {                        // wqkvt[n][k] = w_qkv[k][n]
    wqkvt[i] = f2bf(w_qkv[(i & 255) * 768 + (i >> 8)]);
  } else if (i < 262144) {                 // wpt[n][k] = w_proj[k][n]
    int j = i - 196608;
    wpt[j] = f2bf(w_proj[(j & 255) * 256 + (j >> 8)]);
  } else {
    int j = i - 262144;
    int jr = j & 3, ln = (j >> 2) & 15, g = (j >> 6) & 3;
    int nt = (j >> 8) & 3, mt = (j >> 10) & 3, h = j >> 12;
    int q = 16 * nt + ln;                  // query token
    int k = 16 * mt + 4 * g + jr;          // key token
    int idx = ((q >> 3) - (k >> 3) + 7) * 15 + ((q & 7) - (k & 7) + 7);
    rb2[j] = bias_table[idx * 8 + h];
  }
}

// ---- fused: stage x -> V -> Q/K -> attention -> proj; ROLLED loops --------
// (small code footprint: the fully-unrolled version streams ~60 KB of text
//  through the 32 KB I$ with zero reuse — suspected dominant stall)
__global__ __launch_bounds__(512, 4) void fused_kernel(
    const float* __restrict__ x, const unsigned short* __restrict__ wqkvt,
    const float* __restrict__ b_qkv, const unsigned short* __restrict__ wpt,
    const float* __restrict__ b_proj, const float* __restrict__ rb2,
    float* __restrict__ y) {
  // LDS: XL [64][256] bf16 swizzled at 0 (32 KiB);
  // per-wave region at 16384 + h*2560: first V^T [32][72], later AO [64][40]
  __shared__ unsigned short sm[36864];     // 72 KiB -> 2 blocks/CU
  int wi = blockIdx.x;
  int tid = threadIdx.x;
  int h = tid >> 6, lane = tid & 63, ln = lane & 15, g = lane >> 4;
  unsigned short* R1 = sm + 16384 + h * 2560;

  // -------- phase 0: stage window x -> XL bf16 (swizzled) --------
  int tb = wi * 64;
#pragma unroll 1
  for (int r = 0; r < 2; ++r) {
    int u = tid + 512 * r;
    int tok = u >> 4, ck = u & 15;
    const float4* s4 = (const float4*)(x + src_off(tb + tok) + ck * 16);
    float4 f0 = s4[0], f1 = s4[1], f2 = s4[2], f3 = s4[3];
    uint4 w0, w1;
    w0.x = pack2(f0.x, f0.y); w0.y = pack2(f0.z, f0.w);
    w0.z = pack2(f1.x, f1.y); w0.w = pack2(f1.z, f1.w);
    w1.x = pack2(f2.x, f2.y); w1.y = pack2(f2.z, f2.w);
    w1.z = pack2(f3.x, f3.y); w1.w = pack2(f3.z, f3.w);
    int base = tok * 512 + ck * 32, swz = (tok & 7) << 4;
    *(uint4*)((char*)sm + ((base) ^ swz)) = w0;
    *(uint4*)((char*)sm + ((base + 16) ^ swz)) = w1;
  }
  __syncthreads();

  // -------- pass V (first, so av dies early): M = tokens, N = d --------
  {
    f32x4 av[4][2] = {};
#pragma unroll 1
    for (int ks = 0; ks < 8; ++ks) {
      bf16x8 xf[4];
#pragma unroll
      for (int t = 0; t < 4; ++t) {
        int row = 16 * t + ln;
        xf[t] = *(const bf16x8*)((char*)sm + ((row * 512 + ks * 64 + 16 * g) ^ ((row & 7) << 4)));
      }
      bf16x8 wv[2];
#pragma unroll
      for (int dt = 0; dt < 2; ++dt)
        wv[dt] = *(const bf16x8*)(wqkvt + (512 + 32 * h + 16 * dt + ln) * 256 + ks * 32 + 8 * g);
#pragma unroll
      for (int mt = 0; mt < 4; ++mt)
#pragma unroll
        for (int dt = 0; dt < 2; ++dt)
          av[mt][dt] = MFMA(xf[mt], wv[dt], av[mt][dt]);
    }
    // V^T -> per-wave LDS [32][72] in pack8-PERMUTED column order (r6-verified):
    // token t = 16mt+4g+jr -> column 32*(mt>>1) + 8g + 4*(mt&1) + jr
#pragma unroll
    for (int dt = 0; dt < 2; ++dt) {
      float bv_ = b_qkv[512 + 32 * h + 16 * dt + ln];
#pragma unroll
      for (int mt = 0; mt < 4; ++mt) {
        ushort4 vp;
        vp.x = f2bf(av[mt][dt][0] + bv_); vp.y = f2bf(av[mt][dt][1] + bv_);
        vp.z = f2bf(av[mt][dt][2] + bv_); vp.w = f2bf(av[mt][dt][3] + bv_);
        *(ushort4*)&R1[(16 * dt + ln) * 72 + 32 * (mt >> 1) + 8 * g + 4 * (mt & 1)] = vp;
      }
    }
  }

  // -------- pass Q/K (transposed: M = head-dim d, N = tokens) --------
  bf16x8 qf[4], kf[4];
  {
    f32x4 accq[2][4] = {}, acck[2][4] = {};
#pragma unroll 1
    for (int ks = 0; ks < 8; ++ks) {
      bf16x8 xf[4];
#pragma unroll
      for (int t = 0; t < 4; ++t) {
        int row = 16 * t + ln;
        xf[t] = *(const bf16x8*)((char*)sm + ((row * 512 + ks * 64 + 16 * g) ^ ((row & 7) << 4)));
      }
      bf16x8 wq[2], wk[2];
#pragma unroll
      for (int mt = 0; mt < 2; ++mt) {
        int nr = 32 * h + 16 * mt + ln;
        wq[mt] = *(const bf16x8*)(wqkvt + nr * 256 + ks * 32 + 8 * g);
        wk[mt] = *(const bf16x8*)(wqkvt + (256 + nr) * 256 + ks * 32 + 8 * g);
      }
#pragma unroll
      for (int mt = 0; mt < 2; ++mt)
#pragma unroll
        for (int nt = 0; nt < 4; ++nt) {
          accq[mt][nt] = MFMA(wq[mt], xf[nt], accq[mt][nt]);
          acck[mt][nt] = MFMA(wk[mt], xf[nt], acck[mt][nt]);
        }
    }
    f32x4 bq0 = *(const f32x4*)(b_qkv + 32 * h + 4 * g);
    f32x4 bq1 = *(const f32x4*)(b_qkv + 32 * h + 16 + 4 * g);
    f32x4 bk0 = *(const f32x4*)(b_qkv + 256 + 32 * h + 4 * g);
    f32x4 bk1 = *(const f32x4*)(b_qkv + 256 + 32 * h + 16 + 4 * g);
    const float sc = 0.17677669529663687f;
#pragma unroll
    for (int nt = 0; nt < 4; ++nt) {
      qf[nt] = pack8((accq[0][nt] + bq0) * sc, (accq[1][nt] + bq1) * sc);
      kf[nt] = pack8(acck[0][nt] + bk0, acck[1][nt] + bk1);
    }
  }

  // -------- S^T = K·Q^T with bias preloaded --------
  f32x4 st[4][4];
  const float* rbw = rb2 + h * 4096;
#pragma unroll
  for (int mt = 0; mt < 4; ++mt)
#pragma unroll
    for (int nt = 0; nt < 4; ++nt)
      st[mt][nt] = *(const f32x4*)(rbw + ((((mt * 4 + nt) * 4 + g) * 16 + ln) * 4));
#pragma unroll
  for (int mt = 0; mt < 4; ++mt)
#pragma unroll
    for (int nt = 0; nt < 4; ++nt)
      st[mt][nt] = MFMA(kf[mt], qf[nt], st[mt][nt]);

  // vf re-read from LDS (wave-local; latency hides under softmax VALU)
  bf16x8 vf[2][2];
#pragma unroll
  for (int kk = 0; kk < 2; ++kk)
#pragma unroll
    for (int nd = 0; nd < 2; ++nd)
      vf[kk][nd] = *(const bf16x8*)&R1[(16 * nd + ln) * 72 + 32 * kk + 8 * g];

  // -------- softmax + progressive bf16 pack (st -> pb; stays unrolled:
  //          st/pb runtime-indexing would go to scratch) --------
  bf16x8 pb[2][4];
#pragma unroll
  for (int nt = 0; nt < 4; ++nt) {
    float mx = st[0][nt][0];
#pragma unroll
    for (int mt = 0; mt < 4; ++mt)
#pragma unroll
      for (int jr = 0; jr < 4; ++jr) mx = fmaxf(mx, st[mt][nt][jr]);
    mx = fmaxf(mx, __shfl_xor(mx, 16));
    mx = fmaxf(mx, __shfl_xor(mx, 32));
    float sum = 0.f;
#pragma unroll
    for (int mt = 0; mt < 4; ++mt)
#pragma unroll
      for (int jr = 0; jr < 4; ++jr) {
        float p = __expf(st[mt][nt][jr] - mx);
        st[mt][nt][jr] = p; sum += p;
      }
    sum += __shfl_xor(sum, 16);
    sum += __shfl_xor(sum, 32);
    float inv = 1.f / sum;
    pb[0][nt] = pack8(st[0][nt] * inv, st[1][nt] * inv);
    pb[1][nt] = pack8(st[2][nt] * inv, st[3][nt] * inv);
  }

  // -------- PV: O^T = V^T · P^T --------
  f32x4 o[2][4] = {};
#pragma unroll
  for (int kk = 0; kk < 2; ++kk)
#pragma unroll
    for (int dt = 0; dt < 2; ++dt)
#pragma unroll
      for (int nt = 0; nt < 4; ++nt)
        o[dt][nt] = MFMA(vf[kk][dt], pb[kk][nt], o[dt][nt]);

  // -------- AO -> per-wave LDS (overwrites V^T region; wave-local order ok)
#pragma unroll
  for (int dt = 0; dt < 2; ++dt)
#pragma unroll
    for (int nt = 0; nt < 4; ++nt) {
      uint2 vp;
      vp.x = pack2(o[dt][nt][0], o[dt][nt][1]);
      vp.y = pack2(o[dt][nt][2], o[dt][nt][3]);
      *(uint2*)&R1[(16 * nt + ln) * 40 + 16 * dt + 4 * g] = vp;
    }
  __syncthreads();

  // -------- proj: K-step ks = head ks's AO region (rolled) --------
  f32x4 a2[4][2] = {};
#pragma unroll 1
  for (int ks = 0; ks < 8; ++ks) {
    const unsigned short* AO = sm + 16384 + ks * 2560;
    bf16x8 af2[4], bf2[2];
#pragma unroll
    for (int mt = 0; mt < 4; ++mt)
      af2[mt] = *(const bf16x8*)&AO[(16 * mt + ln) * 40 + 8 * g];
#pragma unroll
    for (int nt = 0; nt < 2; ++nt)
      bf2[nt] = *(const bf16x8*)(wpt + (32 * h + 16 * nt + ln) * 256 + ks * 32 + 8 * g);
#pragma unroll
    for (int mt = 0; mt < 4; ++mt) {
      a2[mt][0] = MFMA(af2[mt], bf2[0], a2[mt][0]);
      a2[mt][1] = MFMA(af2[mt], bf2[1], a2[mt][1]);
    }
  }
  // epilogue: un-shift scatter + proj bias (hoisted bases; a2 static-indexed)
  // n = 16mt+4g+jr:  n>>3 = 2mt+(g>>1),  n&7 = 4(g&1)+jr
  int b = wi >> 10, wr = (wi >> 5) & 31, wc = wi & 31;
  int hb = wr * 8 + (g >> 1) + 4;
  int wb = wc * 8 + 4 * (g & 1) + 4;
  int colb = 32 * h + ln;
  float bp0 = b_proj[colb], bp1 = b_proj[colb + 16];
#pragma unroll
  for (int mt = 0; mt < 4; ++mt) {
    int hh = (hb + 2 * mt) & 255;
#pragma unroll
    for (int jr = 0; jr < 4; ++jr) {
      int ww = (wb + jr) & 255;
      float* yp = y + (((((b << 8) | hh) << 8) | ww) << 8) + colb;
      yp[0]  = a2[mt][0][jr] + bp0;
      yp[16] = a2[mt][1][jr] + bp1;
    }
  }
}

extern "C" void kernel_launch(void* const* d_in, const int* in_sizes, int n_in,
                              void* d_out, int out_size, void* d_ws, size_t ws_size,
                              hipStream_t stream) {
  const float* x          = (const float*)d_in[0];
  const float* w_qkv      = (const float*)d_in[1];
  const float* b_qkv      = (const float*)d_in[2];
  const float* w_proj     = (const float*)d_in[3];
  const float* b_proj     = (const float*)d_in[4];
  const float* bias_table = (const float*)d_in[5];
  char* ws = (char*)d_ws;
  // ws layout: wqkvt 384 KiB | wpt 128 KiB | rb2 128 KiB
  unsigned short* wqkvt = (unsigned short*)(ws);
  unsigned short* wpt   = (unsigned short*)(ws + 393216);
  float* rb2            = (float*)(ws + 524288);
  float* y = (float*)d_out;

  prep_kernel<<<1152, 256, 0, stream>>>(w_qkv, w_proj, bias_table, wqkvt, wpt, rb2);
  fused_kernel<<<4096, 512, 0, stream>>>(x, wqkvt, b_qkv, wpt, b_proj, rb2, y);
}